// Round 9
// baseline (374.555 us; speedup 1.0000x reference)
//
#include <hip/hip_runtime.h>

#define LVAL 256
#define T    32
#define ST   36          // slab row stride (floats): 144 B, 16B-aligned
#define SLAB (T * ST)
#define NB   8
#define NEG  (-1e30f)

typedef float f32x4 __attribute__((ext_vector_type(4)));

// Compiler-only reorder fence (HW DS pipe is in-order within a wave).
#define SOFT_FENCE() asm volatile("" ::: "memory")
#if __has_builtin(__builtin_amdgcn_sched_barrier)
#define SCHED_FENCE() __builtin_amdgcn_sched_barrier(0)
#else
#define SCHED_FENCE() SOFT_FENCE()
#endif

__device__ __forceinline__ size_t sidx(int b, int i, int e) {
    return ((size_t)b << 16) + (i << 8) + e;
}

// ---- coherent (MALL-level) accesses for cross-block data: bypass L1/L2 ----
__device__ __forceinline__ void st_coh4(float* p, f32x4 v) {
    asm volatile("global_store_dwordx4 %0, %1, off sc0 sc1"
                 :: "v"(p), "v"(v) : "memory");
}
__device__ __forceinline__ f32x4 ld_coh4(const float* p) {
    f32x4 v;
    asm volatile("global_load_dwordx4 %0, %1, off sc0 sc1\n\t"
                 "s_waitcnt vmcnt(0)"
                 : "=&v"(v) : "v"(p) : "memory");
    return v;
}
__device__ __forceinline__ void ld_coh4x4(const float* p,
                                          f32x4& a, f32x4& b, f32x4& c, f32x4& d) {
    asm volatile("global_load_dwordx4 %0, %4, off sc0 sc1\n\t"
                 "global_load_dwordx4 %1, %4, off offset:16 sc0 sc1\n\t"
                 "global_load_dwordx4 %2, %4, off offset:32 sc0 sc1\n\t"
                 "global_load_dwordx4 %3, %4, off offset:48 sc0 sc1\n\t"
                 "s_waitcnt vmcnt(0)"
                 : "=&v"(a), "=&v"(b), "=&v"(c), "=&v"(d)
                 : "v"(p) : "memory");
}
__device__ __forceinline__ void st_coh1(int* p, int v) {
    asm volatile("global_store_dword %0, %1, off sc0 sc1"
                 :: "v"(p), "v"(v) : "memory");
}
__device__ __forceinline__ int ld_coh1(const int* p) {
    int v;
    asm volatile("global_load_dword %0, %1, off sc0 sc1\n\t"
                 "s_waitcnt vmcnt(0)"
                 : "=&v"(v) : "v"(p) : "memory");
    return v;
}
__device__ __forceinline__ void spin_flag(int* f) {
    int guard = 0;
    while (ld_coh1(f) == 0) {
        if (++guard > (1 << 20)) break;        // fail loudly, never hang
    }
}

// VALU cross-lane max via DPP
template<int CTRL>
__device__ __forceinline__ float dpp_max(float v) {
#if __has_builtin(__builtin_amdgcn_mov_dpp)
    int o = __builtin_amdgcn_mov_dpp(__builtin_bit_cast(int, v), CTRL, 0xF, 0xF, true);
    return fmaxf(v, __builtin_bit_cast(float, o));
#else
    return fmaxf(v, __shfl_xor(v, CTRL == 0xB1 ? 1 : 2));
#endif
}

// Fresh-value exchange: neighbor cell = lane +/-2. VALU-only: DPP row shift
// inside each 16-lane row + v_readlane patch at the 3 row boundaries. No DS
// op -> never queues behind the prefetch reads (r3/r4's fatal flaw).
__device__ __forceinline__ float exch_vn(float vprev, int c, bool dpos) {
#if __has_builtin(__builtin_amdgcn_mov_dpp) && __has_builtin(__builtin_amdgcn_readlane)
    if (dpos) {
        int o = __builtin_amdgcn_mov_dpp(__builtin_bit_cast(int, vprev),
                                         0x102, 0xF, 0xF, true);   // row_shl:2
        float vn = __builtin_bit_cast(float, o);
        float s0 = __builtin_bit_cast(float,
            __builtin_amdgcn_readlane(__builtin_bit_cast(int, vprev), 16));
        float s1 = __builtin_bit_cast(float,
            __builtin_amdgcn_readlane(__builtin_bit_cast(int, vprev), 32));
        float s2 = __builtin_bit_cast(float,
            __builtin_amdgcn_readlane(__builtin_bit_cast(int, vprev), 48));
        if (c == 7)  vn = s0;
        if (c == 15) vn = s1;
        if (c == 23) vn = s2;
        if (c == 31) vn = NEG;                 // no cell 32 (masked anyway)
        return vn;
    } else {
        int o = __builtin_amdgcn_mov_dpp(__builtin_bit_cast(int, vprev),
                                         0x112, 0xF, 0xF, true);   // row_shr:2
        float vn = __builtin_bit_cast(float, o);
        float s0 = __builtin_bit_cast(float,
            __builtin_amdgcn_readlane(__builtin_bit_cast(int, vprev), 14));
        float s1 = __builtin_bit_cast(float,
            __builtin_amdgcn_readlane(__builtin_bit_cast(int, vprev), 30));
        float s2 = __builtin_bit_cast(float,
            __builtin_amdgcn_readlane(__builtin_bit_cast(int, vprev), 46));
        if (c == 8)  vn = s0;
        if (c == 16) vn = s1;
        if (c == 24) vn = s2;
        if (c == 0)  vn = NEG;                 // no cell -1 (okR masks it)
        return vn;
    }
#else
    return __shfl(vprev, (int)(threadIdx.x & 63) + (dpos ? 2 : -2));
#endif
}

__device__ __forceinline__ float red8(const f32x4 a, const f32x4 b,
                                      const f32x4 c, const f32x4 d) {
    float m0 = fmaxf(a.x + b.x, a.y + b.y);
    float m1 = fmaxf(a.z + b.z, a.w + b.w);
    float m2 = fmaxf(c.x + d.x, c.y + d.y);
    float m3 = fmaxf(c.z + d.z, c.w + d.w);
    return fmaxf(fmaxf(m0, m1), fmaxf(m2, m3));
}

// Phase 1: t[b,i,e] = max_c scores[b,i,e,c] -> f32 s[b][i][e], strict upper only.
__global__ __launch_bounds__(256) void phase1(const float* __restrict__ scores,
                                              float* __restrict__ s,
                                              int* __restrict__ bar) {
    if (blockIdx.x == 0 && blockIdx.y == 0) {
        for (int k = threadIdx.x; k < 2048; k += 256) bar[k] = 0;
    }
    const int i = blockIdx.x, b = blockIdx.y;
    const int sub = threadIdx.x & 15, slot = threadIdx.x >> 4;
    const float* row = scores + ((((size_t)b * LVAL + i) * LVAL) << 6);
    #pragma unroll 4
    for (int m0 = 0; m0 < LVAL; m0 += 16) {
        const int e = m0 + slot;
        if (e > i) {
            float4 v = *((const float4*)(row + ((size_t)e << 6)) + sub);
            float mx = fmaxf(fmaxf(v.x, v.y), fmaxf(v.z, v.w));
            #pragma unroll
            for (int d = 1; d < 16; d <<= 1) mx = fmaxf(mx, __shfl_xor(mx, d));
            if (sub == 0) s[sidx(b, i, e)] = mx;
        }
    }
}

// One wave-synchronous DP step inside a diagonal block (round 0).
template<int LP>
__device__ __forceinline__ void diag_step(int lane, int l,
                                          float (*cur)[ST], float (*curT)[ST],
                                          const float (*tb)[ST]) {
    const int cells = T - l;
    const int P = 1 << LP;
    const int c = lane >> LP, p = lane & (P - 1);
    const bool guard = c < cells;
    const int li = guard ? c : 0;
    const int le = guard ? c + l : 0;
    constexpr int NF = 8 >> LP;
    const float tv = tb[li][le];
    float acc = NEG;
    #pragma unroll
    for (int m = 0; m < NF; ++m) {
        const int k0 = 4 * (p + m * P);
        float4 cu = *(const float4*)&cur[li][k0];
        float4 ct = *(const float4*)&curT[le][k0];
        acc = fmaxf(acc, fmaxf(fmaxf(cu.x + ct.x, cu.y + ct.y),
                               fmaxf(cu.z + ct.z, cu.w + ct.w)));
    }
    acc = dpp_max<0xB1>(acc);                 // xor 1
    if (LP >= 2) acc = dpp_max<0x4E>(acc);    // xor 2
    const float v = acc + tv;
    if (guard && p == 0) cur[li][le] = v;
    if (guard && p == 1) curT[le][li] = v;
}

// ---- pipelined edge pass pieces (r3 math, correctness-proven) --------------
// Step l's full scan is issued during step l-1 (sees diags <= l-2 + stale NEG
// in diag l-1 slots: final-or-NEG, idempotent under max). The 2 fresh diag l-1
// contributions arrive via registers: own pair's vprev + neighbor via exch_vn.
struct EC {
    f32x4 a[4], ct[4], cu[4], bt[4];
    float tv, pr, afr, bfr;
};

__device__ __forceinline__ EC eprefetch(int l, int c, int p,
        const float (*Ae)[ST], const float (*BeT)[ST],
        const float (*cur)[ST], const float (*curT)[ST],
        const float (*tb)[ST], const float (*pre)[ST]) {
    EC e;
    const int delta = l - (T - 1);
    const int ad = delta < 0 ? -delta : delta;
    const int cells = T - ad;
    const bool g = c < cells;
    const int li = g ? (delta < 0 ? c + ad : c) : 0;
    const int le = g ? li + delta : 0;
    e.tv  = tb[li][le];
    e.pr  = pre[li][le];
    e.afr = Ae[li][li + 1];                 // li+1 <= 32 < ST: padding-safe
    e.bfr = BeT[le][le > 0 ? le - 1 : 0];   // masked when le==0
    #pragma unroll
    for (int m = 0; m < 4; ++m) {
        const int k0 = 4 * (p + 2 * m);
        e.a[m]  = *(const f32x4*)&Ae[li][k0];
        e.ct[m] = *(const f32x4*)&curT[le][k0];
        e.cu[m] = *(const f32x4*)&cur[li][k0];
        e.bt[m] = *(const f32x4*)&BeT[le][k0];
    }
    return e;
}

__device__ __forceinline__ float ecompute(int l, int c, int p, int D,
        const EC& e, float vprev, float vn,
        float (*cur)[ST], float (*curT)[ST]) {
    const int delta = l - (T - 1);
    const int ad = delta < 0 ? -delta : delta;
    const int cells = T - ad;
    const bool g = c < cells;
    const int li = g ? (delta < 0 ? c + ad : c) : 0;
    const int le = g ? li + delta : 0;
    const bool dpos = delta > 0;
    float acc = e.pr;
    #pragma unroll
    for (int m = 0; m < 4; ++m)
        acc = fmaxf(acc, red8(e.a[m], e.ct[m], e.cu[m], e.bt[m]));
    const float srcL = dpos ? vn : vprev;   // fresh (li+1, le)
    const float srcR = dpos ? vprev : vn;   // fresh (li, le-1)
    const bool okL = dpos || (c != cells - 1);
    const bool okR = dpos || (c != 0);
    acc = fmaxf(acc, okL ? e.afr + srcL : NEG);
    acc = fmaxf(acc, okR ? srcR + e.bfr : NEG);
    acc = dpp_max<0xB1>(acc);
    const float v = (D == 1 && l == 0) ? e.tv : acc + e.tv;
    if (g && p == 0) cur[li][le] = v;
    if (g && p == 1) curT[le][li] = v;
    return g ? v : NEG;
}

// (max,+) GEMM of one 32x32 K-block
__device__ __forceinline__ void gemm_blk(const float* ATs, const float (*BW)[ST],
                                         int r0, int c0, float (&ag)[4][4]) {
    const float (*AT)[ST] = (const float(*)[ST])ATs;
    #pragma unroll 4
    for (int k = 0; k < T; ++k) {
        f32x4 a4 = *(const f32x4*)&AT[k][r0];
        f32x4 b4 = *(const f32x4*)&BW[k][c0];
        #pragma unroll
        for (int i = 0; i < 4; ++i)
            #pragma unroll
            for (int j = 0; j < 4; ++j)
                ag[i][j] = fmaxf(ag[i][j], a4[i] + b4[j]);
    }
}

// Self-timed dataflow (r7 skeleton): per-tile flags, no global barrier.
__global__ __launch_bounds__(256) void dp_fused(float* __restrict__ s,
                                                const int* __restrict__ lens,
                                                float* __restrict__ out,
                                                int* __restrict__ bar) {
    __shared__ __align__(16) float smem[14 * SLAB];      // 64512 B
    float* ATb = smem;                                   // 6 persistent A^T slabs
    float (*Ae)[ST]  = (float(*)[ST])(smem + 6 * SLAB);
    float (*tb)[ST]  = (float(*)[ST])(smem + 7 * SLAB);
    float (*BeT)[ST] = (float(*)[ST])(smem + 8 * SLAB);
    float (*cur)[ST] = (float(*)[ST])(smem + 9 * SLAB);
    float* BWb = smem + 10 * SLAB;                       // 4 per-wave GEMM slabs
    float (*pre)[ST] = (float(*)[ST])BWb;                // = BW0 (after combine)

    const int b  = blockIdx.x & 7;
    const int bi = blockIdx.x >> 3;
    const int tid = threadIdx.x, wid = tid >> 6, lane = tid & 63;
    const int lr = tid >> 5, lc = tid & 31;
    const int grow = lane >> 1, gc = (lane & 1) * 16;
    const int gly = lane >> 3, glx = lane & 7, r0 = 4 * gly, c0 = 4 * glx;
    const int trow = tid >> 3, tc4 = (tid & 7) * 4;
    float (*BW)[ST] = (float(*)[ST])(BWb + wid * SLAB);
    int* flags = bar + b * 64;                 // flags[K*8 + e] per tile (K,e)

    f32x4 tpb[4], bpb[4];                      // wave1: next tb; wave2: next BeT

    // ---- round 0: wave0 diag DP into Ae; waves 1-3 prefetch tb(D=1)
    if (wid == 0) {
        float (*curT0)[ST] = (float(*)[ST])(BWb + 1 * SLAB);
        float (*t0)[ST]    = (float(*)[ST])(BWb + 2 * SLAB);
        const float4 negv = make_float4(NEG, NEG, NEG, NEG);
        #pragma unroll
        for (int j = 0; j < 4; ++j) {
            float4 v = *(const float4*)&s[sidx(b, bi * T + grow, bi * T + gc + 4 * j)];
            *(float4*)&t0[grow][gc + 4 * j]    = v;
            *(float4*)&Ae[grow][gc + 4 * j]    = negv;
            *(float4*)&curT0[grow][gc + 4 * j] = negv;
        }
        SOFT_FENCE();
        if (lane < T - 1) {                    // w == 1 diagonal = t (final)
            float v = t0[lane][lane + 1];
            Ae[lane][lane + 1] = v;
            curT0[lane + 1][lane] = v;
        }
        SOFT_FENCE();
        #pragma unroll 1
        for (int l = 2; l < T; ++l) {
            if (T - l <= 16) diag_step<2>(lane, l, Ae, curT0, t0);
            else             diag_step<1>(lane, l, Ae, curT0, t0);
            SOFT_FENCE();
        }
        #pragma unroll
        for (int j = 0; j < 4; ++j)            // publish diag (NEG lower kept)
            st_coh4(&s[sidx(b, bi * T + grow, bi * T + gc + 4 * j)],
                    *(const f32x4*)&Ae[grow][gc + 4 * j]);
        asm volatile("s_waitcnt vmcnt(0)" ::: "memory");
        if (lane == 0) st_coh1(&flags[bi * 8 + bi], 1);   // release diag tile
    } else if (bi + 1 < NB) {
        for (int idx = tid - 64; idx < 256; idx += 192) {
            const int row = idx >> 3, c4 = (idx & 7) * 4;
            *(float4*)&tb[row][c4] =
                *(const float4*)&s[sidx(b, bi * T + row, (bi + 1) * T + c4)];
        }
    }

    // ---- rounds 1..NB-1-bi (blocks exit when their row is done) ----
    #pragma unroll 1
    for (int D = 1; D <= NB - 1 - bi; ++D) {
        const int be = bi + D;
        if (tid == 0) {                        // wait exactly what we consume
            spin_flag(&flags[be * 8 + be]);    // diag (set at round 0)
            for (int K = be - 1; K >= bi + 1; --K) spin_flag(&flags[K * 8 + be]);
        }
        __syncthreads();
        if (D == 1) {                          // diag be: head load (flag waited)
            f32x4 v = ld_coh4(&s[sidx(b, be * T + trow, be * T + tc4)]);
            BeT[tc4 + 0][trow] = (trow < tc4 + 0) ? v[0] : NEG;
            BeT[tc4 + 1][trow] = (trow < tc4 + 1) ? v[1] : NEG;
            BeT[tc4 + 2][trow] = (trow < tc4 + 2) ? v[2] : NEG;
            BeT[tc4 + 3][trow] = (trow < tc4 + 3) ? v[3] : NEG;
        }
        // GEMM over middle K blocks: A^T resident in LDS, B staged per wave
        const int nw = (D - 1 < 4) ? (D - 1) : 4;
        float ag[4][4];
        #pragma unroll
        for (int i = 0; i < 4; ++i)
            #pragma unroll
            for (int j = 0; j < 4; ++j) ag[i][j] = NEG;
        for (int K = bi + 1 + wid; K < be; K += 4) {
            const float (*AT)[ST] = (const float(*)[ST])(ATb + (K - bi - 1) * SLAB);
            f32x4 b0, b1, b2, b3;
            ld_coh4x4(&s[sidx(b, K * T + grow, be * T + gc)], b0, b1, b2, b3);
            *(f32x4*)&BW[grow][gc + 0]  = b0;
            *(f32x4*)&BW[grow][gc + 4]  = b1;
            *(f32x4*)&BW[grow][gc + 8]  = b2;
            *(f32x4*)&BW[grow][gc + 12] = b3;
            SOFT_FENCE();
            gemm_blk((const float*)AT, BW, r0, c0, ag);
            SOFT_FENCE();
        }
        if (wid < nw) {
            #pragma unroll
            for (int i = 0; i < 4; ++i)
                *(f32x4*)&BW[r0 + i][c0] =
                    f32x4{ag[i][0], ag[i][1], ag[i][2], ag[i][3]};
        }
        __syncthreads();
        #pragma unroll
        for (int r = 0; r < 4; ++r) {          // combine wave partials -> pre
            const int row = lr + 8 * r;
            float v = NEG;
            for (int w2 = 0; w2 < nw; ++w2)
                v = fmaxf(v, BWb[w2 * SLAB + row * ST + lc]);
            pre[row][lc] = v;
        }
        __syncthreads();
        float (*curT)[ST] = (D == NB - 1) ? (float(*)[ST])(BWb + 1 * SLAB)
                                          : (float(*)[ST])(ATb + (D - 1) * SLAB);
        #pragma unroll
        for (int r = 0; r < 4; ++r) {
            const int row = lr + 8 * r;
            cur[row][lc]  = NEG;
            curT[row][lc] = NEG;
        }
        __syncthreads();
        if (wid == 0) {                        // pipelined edge pass
            const int c = lane >> 1, p = lane & 1;
            EC fA = eprefetch(0, c, p, Ae, BeT, cur, curT, tb, pre);
            EC fB;
            float vprev = NEG;
            SOFT_FENCE();
            #pragma unroll 1
            for (int l = 0; l < 2 * T; l += 2) {
                {
                    float vn = exch_vn(vprev, c, l > T - 1);
                    fB = eprefetch(l + 1, c, p, Ae, BeT, cur, curT, tb, pre);
                    SCHED_FENCE();             // pin prefetch issue above compute
                    vprev = ecompute(l, c, p, D, fA, vprev, vn, cur, curT);
                    SOFT_FENCE();
                }
                {
                    float vn = exch_vn(vprev, c, l + 1 > T - 1);
                    if (l + 2 < 2 * T)
                        fA = eprefetch(l + 2, c, p, Ae, BeT, cur, curT, tb, pre);
                    SCHED_FENCE();
                    vprev = ecompute(l + 1, c, p, D, fB, vprev, vn, cur, curT);
                    SOFT_FENCE();
                }
            }
        } else if (be + 1 < NB) {
            // register preloads for round D+1 during the edge window
            if (wid == 1) {                    // next tb (phase-1 data: cached)
                #pragma unroll
                for (int j = 0; j < 4; ++j)
                    tpb[j] = *(const f32x4*)&s[sidx(b, bi * T + grow,
                                                    (be + 1) * T + gc + 4 * j)];
            }
            if (wid == 2) {                    // next BeT diag (flag-gated coh)
                spin_flag(&flags[(be + 1) * 8 + (be + 1)]);
                #pragma unroll
                for (int j = 0; j < 4; ++j)
                    bpb[j] = ld_coh4(&s[sidx(b, (be + 1) * T + grow,
                                             (be + 1) * T + gc + 4 * j)]);
            }
        }
        __syncthreads();
        {                                      // publish (bi,be) for other rows
            f32x4 pv = *(const f32x4*)&cur[trow][tc4];
            st_coh4(&s[sidx(b, bi * T + trow, be * T + tc4)], pv);
        }
        asm volatile("s_waitcnt vmcnt(0)" ::: "memory");
        __syncthreads();                       // all stores drained block-wide
        if (tid == 0) st_coh1(&flags[bi * 8 + be], 1);   // release tile
        if (be + 1 < NB) {                     // write next-round tb/BeT from regs
            if (wid == 1) {
                #pragma unroll
                for (int j = 0; j < 4; ++j)
                    *(f32x4*)&tb[grow][gc + 4 * j] = tpb[j];
            }
            if (wid == 2) {
                #pragma unroll
                for (int j = 0; j < 4; ++j)
                    #pragma unroll
                    for (int k = 0; k < 4; ++k) {
                        const int col = gc + 4 * j + k;
                        BeT[col][grow] = (grow < col) ? bpb[j][k] : NEG;
                    }
            }
        }
    }

    // Fused finalize: block (b,0) owns row 0, everything needed is in its LDS.
    if (bi == 0 && tid == 0) {
        int len = lens[b];
        len = len < 1 ? 1 : (len > LVAL - 1 ? LVAL - 1 : len);
        const int K = len >> 5, off = len & 31;
        float r;
        if (K == 0)           r = Ae[0][off];
        else if (K == NB - 1) r = cur[0][off];
        else                  r = ATb[(K - 1) * SLAB + off * ST];
        out[b] = r;
    }
}

extern "C" void kernel_launch(void* const* d_in, const int* in_sizes, int n_in,
                              void* d_out, int out_size, void* d_ws, size_t ws_size,
                              hipStream_t stream) {
    const float* scores = (const float*)d_in[0];
    const int*   lens   = (const int*)d_in[1];
    float*       out    = (float*)d_out;
    float*       s      = (float*)d_ws;               // 8 * 256 * 256 f32 = 2 MB
    int*         bar    = (int*)((char*)d_ws + ((size_t)(8) << 16) * sizeof(float));

    phase1<<<dim3(LVAL, 8), 256, 0, stream>>>(scores, s, bar);
    dp_fused<<<64, 256, 0, stream>>>(s, lens, out, bar);
}